// Round 1
// baseline (290.447 us; speedup 1.0000x reference)
//
#include <hip/hip_runtime.h>
#include <hip/hip_bf16.h>

// PointsToBEV round 16. R15 rocprof: k_mlp_mfma FETCH~=WRITE~=103MB --
// symmetric RMW signature of the 1.65M split-cell f32 atomicAdds serviced
// beyond-L2 at 64B/atomic (1.65M x 64B = 105MB each way, matches). Fix:
// ownership scheme. The chunk containing a cell's START plain-stores the
// full row (incl. tail-split partials); a chunk whose head cell started
// earlier stores its partial to a per-chunk staging row (sums[ncells+wv]).
// New k_fixup folds staged partials in with plain adds (atomic only in the
// impossible >64-pts/cell case). Zero atomics in the hot kernel.

#define B_    4
#define NP_   200000
#define CH    80
#define COUT_ 128
#define BEVH  128
#define BEVW  128
#define HW_   (BEVH * BEVW)
#define NCHK  (NP_ / 64)        // 3125 chunks per batch (NP_ % 64 == 0)

// Per-batch: cnt(HW u32) + sums(HW*CH f32) + staging(NCHK*CH f32) +
// offs(HW u32 +pad) + cursor(HW u32) + psorted(NP float4) + scell(NP u32)
#define PER_BATCH ((size_t)HW_ * 332 + (size_t)NP_ * 25)
#define EXTRA_BYTES 512

#define MAGIC_OFF   128
#define SCRATCH_OFF 256

typedef _Float16 half4_t __attribute__((ext_vector_type(4)));
typedef _Float16 half8_t __attribute__((ext_vector_type(8)));
typedef float    f32x4_t __attribute__((ext_vector_type(4)));

#define HSTR 104   // W2T k-stride in f16 (52 dwords -> 2-way banks, free)
#define ESTR 72    // embT pt-stride in f16 (36 dwords -> 2-way banks, free)

__device__ __forceinline__ float bf2f(unsigned short u) {
    return __uint_as_float(((unsigned int)u) << 16);
}

// ---------------------------------------------------------------------------
// dtype probes: flags[0]=params fp32, flags[1]=points fp32.
// ---------------------------------------------------------------------------
__global__ void k_detect(const unsigned short* __restrict__ w1bits,
                         const unsigned short* __restrict__ ptsbits,
                         unsigned int* __restrict__ flags) {
    const int t = threadIdx.x;
    const int which = blockIdx.x;
    const unsigned short* src = which ? ptsbits : w1bits;
    const int n = which ? 512 : 320;
    float m = 0.0f;
    for (int i = t; i < n; i += 64) {
        const float a = fabsf(bf2f(src[i]));
        if (a == a) m = fmaxf(m, a);
    }
#pragma unroll
    for (int off = 32; off > 0; off >>= 1)
        m = fmaxf(m, __shfl_down(m, off));
    if (t == 0) flags[which] = (m > 1.0e6f) ? 1u : 0u;
}

__global__ __launch_bounds__(256) void k_zero(float4* __restrict__ p, int n4) {
    const float4 z = {0.0f, 0.0f, 0.0f, 0.0f};
    for (int i = blockIdx.x * 256 + threadIdx.x; i < n4; i += gridDim.x * 256)
        p[i] = z;
}

__device__ __forceinline__ int cell_of(float px, float py, int bloc) {
    const int ix = (int)floorf((px + 50.0f) / 0.78125f);
    const int iy = (int)floorf((py + 50.0f) / 0.78125f);
    if (ix < 0 || ix >= BEVW || iy < 0 || iy >= BEVH) return -1;
    return bloc * HW_ + iy * BEVW + ix;
}

__device__ __forceinline__ void load_pt(const void* pts_raw, size_t pidx, int pf32,
                                        float& px, float& py, float& pz, float& pw) {
    if (pf32) {
        const float4 p = ((const float4*)pts_raw)[pidx];
        px = p.x; py = p.y; pz = p.z; pw = p.w;
    } else {
        const ushort4 p = ((const ushort4*)pts_raw)[pidx];
        px = bf2f(p.x); py = bf2f(p.y); pz = bf2f(p.z); pw = bf2f(p.w);
    }
}

// ---------------------------------------------------------------------------
// Phase A: histogram.
// ---------------------------------------------------------------------------
__global__ __launch_bounds__(256) void k_bin(
    const void* __restrict__ pts_raw,
    const unsigned int* __restrict__ flags,
    unsigned int* __restrict__ cnt,
    int b0, int npts)
{
    const int gid = blockIdx.x * 256 + threadIdx.x;
    if (gid >= npts) return;
    float px, py, pz, pw;
    load_pt(pts_raw, (size_t)b0 * NP_ + gid, (int)flags[1], px, py, pz, pw);
    const int g = cell_of(px, py, gid / NP_);
    if (g >= 0) atomicAdd(&cnt[g], 1u);
}

// ---------------------------------------------------------------------------
// Phase B1: per-block (1024 cells) sums.
// ---------------------------------------------------------------------------
__global__ __launch_bounds__(256) void k_scan_part(
    const unsigned int* __restrict__ cnt,
    unsigned int* __restrict__ bsums)
{
    __shared__ unsigned int sd[256];
    const int t = threadIdx.x;
    const int i0 = blockIdx.x * 1024 + t * 4;
    unsigned int s = cnt[i0] + cnt[i0 + 1] + cnt[i0 + 2] + cnt[i0 + 3];
    sd[t] = s;
    __syncthreads();
    for (int d = 128; d > 0; d >>= 1) {
        if (t < d) sd[t] += sd[t + d];
        __syncthreads();
    }
    if (t == 0) bsums[blockIdx.x] = sd[0];
}

// ---------------------------------------------------------------------------
// Phase B2: apply prefix -> offs (+sentinel) and cursor.
// ---------------------------------------------------------------------------
__global__ __launch_bounds__(256) void k_scan_apply(
    const unsigned int* __restrict__ cnt,
    const unsigned int* __restrict__ bsums,
    unsigned int* __restrict__ offs,
    unsigned int* __restrict__ cursor,
    int nblocks, int n)
{
    __shared__ unsigned int sd[256];
    __shared__ unsigned int sBase;
    const int t = threadIdx.x;
    const int blk = blockIdx.x;
    const int i0 = blk * 1024 + t * 4;
    unsigned int c0 = cnt[i0], c1 = cnt[i0 + 1], c2 = cnt[i0 + 2], c3 = cnt[i0 + 3];
    const unsigned int s4 = c0 + c1 + c2 + c3;
    sd[t] = s4;
    if (t == 0) {
        unsigned int b = 0;
        for (int j = 0; j < blk; ++j) b += bsums[j];
        sBase = b;
    }
    __syncthreads();
    for (int d = 1; d < 256; d <<= 1) {
        const unsigned int add = (t >= d) ? sd[t - d] : 0u;
        __syncthreads();
        sd[t] += add;
        __syncthreads();
    }
    unsigned int run = sBase + sd[t] - s4;    // exclusive prefix
    offs[i0] = run;     cursor[i0] = run;     run += c0;
    offs[i0 + 1] = run; cursor[i0 + 1] = run; run += c1;
    offs[i0 + 2] = run; cursor[i0 + 2] = run; run += c2;
    offs[i0 + 3] = run; cursor[i0 + 3] = run; run += c3;
    if (blk == nblocks - 1 && t == 255) offs[n] = run;
}

// ---------------------------------------------------------------------------
// Phase C: materialize the sort — write point data + cell into sorted slots.
// ---------------------------------------------------------------------------
__global__ __launch_bounds__(256) void k_scatteridx(
    const void* __restrict__ pts_raw,
    const unsigned int* __restrict__ flags,
    unsigned int* __restrict__ cursor,
    float4* __restrict__ psorted,
    unsigned int* __restrict__ scell,
    int b0, int npts)
{
    const int gid = blockIdx.x * 256 + threadIdx.x;
    if (gid >= npts) return;
    float px, py, pz, pw;
    load_pt(pts_raw, (size_t)b0 * NP_ + gid, (int)flags[1], px, py, pz, pw);
    const int g = cell_of(px, py, gid / NP_);
    if (g < 0) return;
    const unsigned int pos = atomicAdd(&cursor[g], 1u);
    float4 v; v.x = px; v.y = py; v.z = pz; v.w = pw;
    psorted[pos] = v;
    scell[pos] = (unsigned int)g;
}

// ---------------------------------------------------------------------------
// Phase D (persistent MFMA): waves grid-stride over 64-point chunks.
// Sequential psorted/scell reads; A-fragments born in registers; MFMA1
// (emb = h . W2) then MFMA2 (cellsums = S^T . emb) per 16-ch tile.
// Ownership stores: chunk containing a cell's start writes sums[g] (plain,
// full row); a head cell that started earlier goes to staging row
// sums[ncells+wv]. NO atomics here (R16).
// ---------------------------------------------------------------------------
__global__ __launch_bounds__(256, 4) void k_mlp_mfma(
    const float4* __restrict__ psorted,
    const unsigned int* __restrict__ scell,
    const void* __restrict__ W1_raw,
    const void* __restrict__ b1_raw,
    const void* __restrict__ W2_raw,
    const void* __restrict__ b2_raw,
    const unsigned int* __restrict__ flags,
    unsigned int* __restrict__ magic,
    const unsigned int* __restrict__ offs,    // ncells+1 (sentinel = total)
    float* __restrict__ sums,                 // (ncells + nchunks) x 80, pre-zeroed cells
    int ncells)
{
    __shared__ float sW1[4 * CH];             // [f][k]
    __shared__ float sb1[CH];
    __shared__ float sb2f[CH];
    __shared__ _Float16 sW2T[80 * HSTR];      // [ch_out][k], k 80..95 zero
    __shared__ _Float16 sEmb[4][16 * ESTR];   // per-wave embT slice [ch16][pt]
    __shared__ unsigned int sCellG[4][64];

    const int t = threadIdx.x;
    const int wf32 = (int)flags[0];

    if (wf32) {
        const float* W1 = (const float*)W1_raw;
        const float* b1 = (const float*)b1_raw;
        const float* b2 = (const float*)b2_raw;
        for (int i = t; i < 4 * CH; i += 256) sW1[i] = W1[i];
        if (t < CH) { sb1[t] = b1[t]; sb2f[t] = b2[t]; }
        const float* W2 = (const float*)W2_raw;
        for (int i = t; i < 80 * HSTR; i += 256) {
            const int row = i / HSTR, k = i % HSTR;
            sW2T[i] = (_Float16)((k < 80) ? W2[k * CH + row] : 0.0f);
        }
    } else {
        const unsigned short* W1 = (const unsigned short*)W1_raw;
        const unsigned short* b1 = (const unsigned short*)b1_raw;
        const unsigned short* b2 = (const unsigned short*)b2_raw;
        for (int i = t; i < 4 * CH; i += 256) sW1[i] = bf2f(W1[i]);
        if (t < CH) { sb1[t] = bf2f(b1[t]); sb2f[t] = bf2f(b2[t]); }
        const unsigned short* W2 = (const unsigned short*)W2_raw;
        for (int i = t; i < 80 * HSTR; i += 256) {
            const int row = i / HSTR, k = i % HSTR;
            sW2T[i] = (_Float16)((k < 80) ? bf2f(W2[k * CH + row]) : 0.0f);
        }
    }
    __syncthreads();

    if (blockIdx.x == 0 && t == 0) *magic = 0xCAFEBABEu;

    const int end = (int)offs[ncells];
    const int lane = t & 63;
    const int wid = t >> 6;
    const int m15 = lane & 15;
    const int quad = lane >> 4;
    const int totalWaves = gridDim.x * 4;
    const int nChunks = (end + 63) >> 6;

    for (int wv = blockIdx.x * 4 + wid; wv < nChunks; wv += totalWaves) {
        const int chunkStart = wv * 64;
        const int p = chunkStart + lane;
        const bool active = p < end;

        int g = -1;
        float px = 0.0f, py = 0.0f, pz = 0.0f, pw = 0.0f;
        if (active) {
            const float4 ps = psorted[p];       // sequential, coalesced
            px = ps.x; py = ps.y; pz = ps.z; pw = ps.w;
            g = (int)scell[p];                  // sequential, coalesced
        }

        // ---- segment bookkeeping (R13-verified).
        const int gprev = __shfl_up(g, 1);
        const bool isHead = active && (lane == 0 || gprev != g);
        const unsigned long long headmask = __ballot(isHead);
        const int cellLocal = active
            ? (__popcll(headmask << (63 - lane)) - 1) : 255;
        const int ncellsW = __popcll(headmask);
        if (isHead) {
            // Ownership: cell start within this chunk -> write sums[g] direct.
            // Head cell that started earlier -> per-chunk staging row.
            unsigned int row = (unsigned int)g;
            if (cellLocal == 0) {
                const unsigned int o = offs[g];
                if (o < (unsigned int)chunkStart)
                    row = (unsigned int)(ncells + wv);
            }
            sCellG[wid][cellLocal] = row;
        }

        // ---- gather the 4 points this lane's A-fragments cover.
        float pmx[4], pmy[4], pmz[4], pmw[4];
#pragma unroll
        for (int mt = 0; mt < 4; ++mt) {
            const int src = mt * 16 + m15;
            pmx[mt] = __shfl(px, src);
            pmy[mt] = __shfl(py, src);
            pmz[mt] = __shfl(pz, src);
            pmw[mt] = __shfl(pw, src);
        }

        // ---- layer 1 transposed: A-frag values born in registers.
        half8_t Af[3][4];
#pragma unroll
        for (int ks = 0; ks < 3; ++ks) {
            const int kb = ks * 32 + quad * 8;
            if (kb < 80) {
                const float4 wa0 = *(const float4*)&sW1[0 * CH + kb];
                const float4 wb0 = *(const float4*)&sW1[0 * CH + kb + 4];
                const float4 wa1 = *(const float4*)&sW1[1 * CH + kb];
                const float4 wb1 = *(const float4*)&sW1[1 * CH + kb + 4];
                const float4 wa2 = *(const float4*)&sW1[2 * CH + kb];
                const float4 wb2 = *(const float4*)&sW1[2 * CH + kb + 4];
                const float4 wa3 = *(const float4*)&sW1[3 * CH + kb];
                const float4 wb3 = *(const float4*)&sW1[3 * CH + kb + 4];
                const float4 ba  = *(const float4*)&sb1[kb];
                const float4 bb  = *(const float4*)&sb1[kb + 4];
                float w0[8] = {wa0.x, wa0.y, wa0.z, wa0.w, wb0.x, wb0.y, wb0.z, wb0.w};
                float w1[8] = {wa1.x, wa1.y, wa1.z, wa1.w, wb1.x, wb1.y, wb1.z, wb1.w};
                float w2[8] = {wa2.x, wa2.y, wa2.z, wa2.w, wb2.x, wb2.y, wb2.z, wb2.w};
                float w3[8] = {wa3.x, wa3.y, wa3.z, wa3.w, wb3.x, wb3.y, wb3.z, wb3.w};
                float bv[8] = {ba.x, ba.y, ba.z, ba.w, bb.x, bb.y, bb.z, bb.w};
#pragma unroll
                for (int mt = 0; mt < 4; ++mt) {
                    half8_t v;
#pragma unroll
                    for (int j = 0; j < 8; ++j) {
                        float hv = bv[j];
                        hv = fmaf(pmx[mt], w0[j], hv);
                        hv = fmaf(pmy[mt], w1[j], hv);
                        hv = fmaf(pmz[mt], w2[j], hv);
                        hv = fmaf(pmw[mt], w3[j], hv);
                        v[j] = (_Float16)fmaxf(hv, 0.0f);
                    }
                    Af[ks][mt] = v;
                }
            } else {
                const half8_t z8 = {0, 0, 0, 0, 0, 0, 0, 0};
#pragma unroll
                for (int mt = 0; mt < 4; ++mt) Af[ks][mt] = z8;
            }
        }

        // ---- selector columns for MFMA2.
        int cl[2][8];
#pragma unroll
        for (int ks2 = 0; ks2 < 2; ++ks2)
#pragma unroll
            for (int j = 0; j < 8; ++j)
                cl[ks2][j] = __shfl(cellLocal, ks2 * 32 + quad * 8 + j);

        const int nMt2 = (ncellsW + 15) >> 4;
        _Float16* embT = &sEmb[wid][0];

        // ---- per 16-channel tile: MFMA1 -> epilogue -> embT -> MFMA2 -> store.
#pragma unroll 1
        for (int nt = 0; nt < 5; ++nt) {
            f32x4_t acc[4];
#pragma unroll
            for (int mt = 0; mt < 4; ++mt) acc[mt] = (f32x4_t){0.0f, 0.0f, 0.0f, 0.0f};

#pragma unroll
            for (int ks = 0; ks < 3; ++ks) {
                const half8_t Bf = *(const half8_t*)
                    &sW2T[(nt * 16 + m15) * HSTR + ks * 32 + quad * 8];
#pragma unroll
                for (int mt = 0; mt < 4; ++mt)
                    acc[mt] = __builtin_amdgcn_mfma_f32_16x16x32_f16(
                        Af[ks][mt], Bf, acc[mt], 0, 0, 0);
            }

            // bias + relu -> embT slice [ch16=m15][pt].
            const float bb2 = sb2f[nt * 16 + m15];
#pragma unroll
            for (int mt = 0; mt < 4; ++mt) {
                const f32x4_t a = acc[mt];
                half4_t v;
                v[0] = (_Float16)fmaxf(a[0] + bb2, 0.0f);
                v[1] = (_Float16)fmaxf(a[1] + bb2, 0.0f);
                v[2] = (_Float16)fmaxf(a[2] + bb2, 0.0f);
                v[3] = (_Float16)fmaxf(a[3] + bb2, 0.0f);
                *(half4_t*)&embT[m15 * ESTR + mt * 16 + quad * 4] = v;
            }

            half8_t B2[2];
#pragma unroll
            for (int ks2 = 0; ks2 < 2; ++ks2)
                B2[ks2] = *(const half8_t*)&embT[m15 * ESTR + ks2 * 32 + quad * 8];

            for (int mt2 = 0; mt2 < nMt2; ++mt2) {
                const int m2 = mt2 * 16 + m15;
                f32x4_t acc2 = (f32x4_t){0.0f, 0.0f, 0.0f, 0.0f};
#pragma unroll
                for (int ks2 = 0; ks2 < 2; ++ks2) {
                    half8_t A2;
#pragma unroll
                    for (int j = 0; j < 8; ++j)
                        A2[j] = (cl[ks2][j] == m2) ? (_Float16)1 : (_Float16)0;
                    acc2 = __builtin_amdgcn_mfma_f32_16x16x32_f16(
                        A2, B2[ks2], acc2, 0, 0, 0);
                }
#pragma unroll
                for (int r = 0; r < 4; ++r) {
                    const int cell = mt2 * 16 + quad * 4 + r;
                    if (cell < ncellsW) {
                        const unsigned int row = sCellG[wid][cell];
                        sums[(size_t)row * CH + nt * 16 + m15] = acc2[r];
                    }
                }
            }
        }
    }
}

// ---------------------------------------------------------------------------
// Phase D2: fold staged head-partials into their cells. One block per chunk
// boundary; plain add (each staging slot targets a distinct cell unless a
// cell spans >64 points, in which case fall back to atomic -- never happens
// at ~10 pts/cell but keeps us correct for any data).
// ---------------------------------------------------------------------------
__global__ __launch_bounds__(128) void k_fixup(
    const unsigned int* __restrict__ offs,
    const unsigned int* __restrict__ cnt,
    const unsigned int* __restrict__ scell,
    float* __restrict__ sums,
    int ncells)
{
    const int b = blockIdx.x + 1;             // chunk index 1..nChunks-1
    const int start = b * 64;
    const int end = (int)offs[ncells];
    if (start >= end) return;
    const unsigned int g = scell[start];
    const unsigned int o = offs[g];
    if (o >= (unsigned int)start) return;     // boundary fell on a cell edge
    const int t = threadIdx.x;
    const float* __restrict__ src = &sums[((size_t)ncells + (size_t)b) * CH];
    float* __restrict__ dst = &sums[(size_t)g * CH];
    const bool multi = (o + cnt[g] > (unsigned int)(start + 64));
    if (t < CH) {
        const float v = src[t];
        if (multi) atomicAdd(&dst[t], v);
        else dst[t] += v;
    }
}

// ---------------------------------------------------------------------------
// Head: mean -> 1x1 conv -> BN -> relu -> out (fp32). Mean staged f16.
// ---------------------------------------------------------------------------
#define MPAD 84

__global__ __launch_bounds__(256) void k_head(
    const float* __restrict__ sums,
    const unsigned int* __restrict__ cnt,
    const void* __restrict__ Wp_raw,
    const void* __restrict__ bp_raw,
    const void* __restrict__ gamma_raw,
    const void* __restrict__ beta_raw,
    const void* __restrict__ rmean_raw,
    const void* __restrict__ rvar_raw,
    const unsigned int* __restrict__ flags,
    float* __restrict__ out,
    int b0)
{
    __shared__ float sWp[CH * COUT_];
    __shared__ _Float16 sMean[BEVW * MPAD];
    __shared__ float sAlpha[COUT_], sDelta[COUT_];

    const int t = threadIdx.x;
    const int blk = blockIdx.x;
    const int bl = blk >> 7, hrow = blk & 127;
    const int bg = b0 + bl;
    const int wf32 = (int)flags[0];

    if (wf32) {
        const float* Wp = (const float*)Wp_raw;
        for (int i = t; i < CH * COUT_; i += 256) sWp[i] = Wp[i];
        if (t < COUT_) {
            const float rs = rsqrtf(((const float*)rvar_raw)[t] + 1e-5f);
            const float al = ((const float*)gamma_raw)[t] * rs;
            sAlpha[t] = al;
            sDelta[t] = al * (((const float*)bp_raw)[t] - ((const float*)rmean_raw)[t])
                        + ((const float*)beta_raw)[t];
        }
    } else {
        const unsigned short* Wp = (const unsigned short*)Wp_raw;
        for (int i = t; i < CH * COUT_; i += 256) sWp[i] = bf2f(Wp[i]);
        if (t < COUT_) {
            const float rs = rsqrtf(bf2f(((const unsigned short*)rvar_raw)[t]) + 1e-5f);
            const float al = bf2f(((const unsigned short*)gamma_raw)[t]) * rs;
            sAlpha[t] = al;
            sDelta[t] = al * (bf2f(((const unsigned short*)bp_raw)[t])
                              - bf2f(((const unsigned short*)rmean_raw)[t]))
                        + bf2f(((const unsigned short*)beta_raw)[t]);
        }
    }

    const int cellbase = bl * HW_ + hrow * BEVW;
    for (int i = t; i < BEVW * 20; i += 256) {
        const int w = i / 20, c4 = i % 20;
        const float cn = (float)cnt[cellbase + w];
        const float inv = 1.0f / fmaxf(cn, 1.0f);
        const float4 s = ((const float4*)(sums + (size_t)(cellbase + w) * CH))[c4];
        _Float16* m = &sMean[w * MPAD + c4 * 4];
        m[0] = (_Float16)(s.x * inv);
        m[1] = (_Float16)(s.y * inv);
        m[2] = (_Float16)(s.z * inv);
        m[3] = (_Float16)(s.w * inv);
    }
    __syncthreads();

    const int v = t >> 6;
    const int w = (t & 63) + (v & 1) * 64;
    const int dbase = (v >> 1) * 64;

    float acc[64];
#pragma unroll
    for (int j = 0; j < 64; ++j) acc[j] = 0.0f;

    const _Float16* mrow = &sMean[w * MPAD];
#pragma unroll 2
    for (int c = 0; c < CH; ++c) {
        const float m = (float)mrow[c];
        const float4* wrow = (const float4*)&sWp[c * COUT_ + dbase];
#pragma unroll
        for (int j4 = 0; j4 < 16; ++j4) {
            const float4 wv = wrow[j4];
            acc[j4 * 4 + 0] = fmaf(m, wv.x, acc[j4 * 4 + 0]);
            acc[j4 * 4 + 1] = fmaf(m, wv.y, acc[j4 * 4 + 1]);
            acc[j4 * 4 + 2] = fmaf(m, wv.z, acc[j4 * 4 + 2]);
            acc[j4 * 4 + 3] = fmaf(m, wv.w, acc[j4 * 4 + 3]);
        }
    }

#pragma unroll
    for (int j = 0; j < 64; ++j) {
        const int d = dbase + j;
        float o = fmaxf(fmaf(acc[j], sAlpha[d], sDelta[d]), 0.0f);
        o = fminf(o, 512.0f);
        out[(((size_t)bg * COUT_ + d) * BEVH + hrow) * BEVW + w] = o;
    }
}

// ---------------------------------------------------------------------------
// Diagnostics beacon (insurance; healthy run writes nothing).
// ---------------------------------------------------------------------------
__global__ __launch_bounds__(256) void k_diag(
    const unsigned int* __restrict__ cnt,
    const float* __restrict__ sums,
    const unsigned int* __restrict__ magic,
    const unsigned int* __restrict__ flags,
    float* __restrict__ out,
    int hostbits)
{
    __shared__ float red[256];
    __shared__ unsigned int credu[256];
    const int t = threadIdx.x;

    unsigned int cs = 0;
    for (int i = t; i < HW_; i += 256) cs += cnt[i];
    credu[t] = cs;

    float sl = 0.0f;
    for (int i = t; i < CH * CH; i += 256) sl += fabsf(sums[i]);
    red[t] = sl;
    __syncthreads();

    for (int s = 128; s > 0; s >>= 1) {
        if (t < s) { red[t] += red[t + s]; credu[t] += credu[t + s]; }
        __syncthreads();
    }

    if (t == 0) {
        int code = hostbits;
        if (*magic != 0xCAFEBABEu) code |= 1;
        if (credu[0] < 1000u)      code |= 2;
        if (!(red[0] > 0.0f))      code |= 4;
        if (code) {
            code |= (int)(flags[0] ? 32 : 0);
            code |= (int)(flags[1] ? 64 : 0);
            out[0] = 1024.0f * (float)code;
        }
    }
}

extern "C" void kernel_launch(void* const* d_in, const int* in_sizes, int n_in,
                              void* d_out, int out_size, void* d_ws, size_t ws_size,
                              hipStream_t stream) {
    const void* pts   = d_in[0];
    const void* W1    = d_in[1];
    const void* b1    = d_in[2];
    const void* W2    = d_in[3];
    const void* b2    = d_in[4];
    const void* Wp    = d_in[5];
    const void* bp    = d_in[6];
    const void* gamma = d_in[7];
    const void* beta  = d_in[8];
    const void* rmean = d_in[9];
    const void* rvar  = d_in[10];

    int hostbits = 0;
    if (n_in != 11 ||
        in_sizes[0] != B_ * NP_ * 4 ||
        in_sizes[1] != 4 * CH  || in_sizes[2] != CH ||
        in_sizes[3] != CH * CH || in_sizes[4] != CH ||
        in_sizes[5] != CH * COUT_ || in_sizes[6] != COUT_ ||
        out_size != B_ * COUT_ * HW_)
        hostbits |= 8;
    if (ws_size < SCRATCH_OFF + PER_BATCH + EXTRA_BYTES) hostbits |= 16;

    unsigned int* flags = (unsigned int*)d_ws;
    unsigned int* magic = (unsigned int*)((char*)d_ws + MAGIC_OFF);
    char* base = (char*)d_ws + SCRATCH_OFF;
    const size_t avail = (ws_size > SCRATCH_OFF + EXTRA_BYTES)
                       ? (ws_size - SCRATCH_OFF - EXTRA_BYTES) : PER_BATCH;
    int nb = (int)(avail / PER_BATCH);
    if (nb < 1) nb = 1;
    if (nb > B_) nb = B_;

    // Layout: cnt | sums | staging (contiguous with sums: rows ncells+wv) |
    //         offs(+4) | cursor | psorted (16B-aligned) | scell | bsums
    unsigned int* cnt     = (unsigned int*)base;
    float*        sums    = (float*)(cnt + (size_t)nb * HW_);
    float*        staging = sums + (size_t)nb * HW_ * CH;
    unsigned int* offs    = (unsigned int*)(staging + (size_t)nb * NCHK * CH);
    unsigned int* cursor  = offs + (size_t)nb * HW_ + 4;
    float4*       psorted = (float4*)(cursor + (size_t)nb * HW_);
    unsigned int* scell   = (unsigned int*)(psorted + (size_t)nb * NP_);
    unsigned int* bsums   = scell + (size_t)nb * NP_;

    k_detect<<<2, 64, 0, stream>>>((const unsigned short*)W1,
                                   (const unsigned short*)pts, flags);

    for (int b0 = 0; b0 < B_; b0 += nb) {
        const int bcnt = (B_ - b0 < nb) ? (B_ - b0) : nb;
        const int ncells = bcnt * HW_;
        const int npts   = bcnt * NP_;
        const int nblk   = ncells >> 10;      // 1024 cells per scan block

        // Zero cnt+sums in one pass (contiguous, 81 f32 per cell).
        // Staging rows need no zeroing: k_fixup only reads slots whose
        // write-condition (recomputed from offs/scell) held in k_mlp_mfma.
        k_zero<<<512, 256, 0, stream>>>((float4*)cnt, ncells * 81 / 4);

        k_bin<<<(npts + 255) / 256, 256, 0, stream>>>(
            pts, flags, cnt, b0, npts);

        k_scan_part<<<nblk, 256, 0, stream>>>(cnt, bsums);
        k_scan_apply<<<nblk, 256, 0, stream>>>(cnt, bsums, offs, cursor,
                                               nblk, ncells);

        k_scatteridx<<<(npts + 255) / 256, 256, 0, stream>>>(
            pts, flags, cursor, psorted, scell, b0, npts);

        k_mlp_mfma<<<1024, 256, 0, stream>>>(
            psorted, scell, W1, b1, W2, b2, flags, magic, offs, sums,
            ncells);

        k_fixup<<<bcnt * NCHK - 1, 128, 0, stream>>>(
            offs, cnt, scell, sums, ncells);

        k_head<<<bcnt * BEVH, 256, 0, stream>>>(
            sums, cnt, Wp, bp, gamma, beta, rmean, rvar, flags,
            (float*)d_out, b0);
    }

    k_diag<<<1, 256, 0, stream>>>(cnt, sums, magic, flags,
                                  (float*)d_out, hostbits);
}